// Round 11
// baseline (69.656 us; speedup 1.0000x reference)
//
#include <hip/hip_runtime.h>
#include <math.h>

typedef unsigned int u32;
typedef unsigned long long u64;

// ---------------------------------------------------------------------------
// Output layout (float32, 414 elems):
//  [0..3] confmat [tn,fp,fn,tp]; [4] map_; [5..105] prec_t; [106..206] rec_t;
//  [207..307] ths; [308..408] spec_t; [409..413] recall,precision,specificity,
//  accuracy, loss_out
//
// Round 11: 3 dispatches total.
//  main_pass  (512x1024): R10's 8-elem/iter stream + 5-op d-bin hash + LDS
//             histogram; also zeroes the two last-block gate counters.
//  reduce_scan (128x256): each block OWNS 32 bins (non-atomic -> no memset),
//             last block (threadfence + ACQ_REL agent counter) scans 4096
//             bins -> prefixA.
//  ap_finalize (256x256): AP contributions; last block folds partials and
//             writes all 414 outputs (R9/R10 validated tail math, absmax
//             3.8e-6: interpolated thresholds at logit(th)*256+2048, confmat
//             at bin-2048 edge, per-bin uniform AP ranks).
//
// Workspace: partials NBLK*NBIN*4 (8MB) | fineHist NBIN*8 | prefixA NBIN*8 |
//            apPartial APB*8 | ctrs 2*4
// ---------------------------------------------------------------------------

#define NBIN  4096
#define NBLK  512
#define TPB   1024
#define RBLK  128
#define BPB   (NBIN / RBLK)    // 32 bins per reduce block
#define APB   256

static __device__ __forceinline__ float safe_div_f(float a, float b) {
    return (b > 0.0f) ? (a / fmaxf(b, 1.0f)) : 0.0f;
}

static __device__ __forceinline__ int bin5(float d0, float d1) {
    float x = fminf(fmaxf(fmaf(d1 - d0, 256.0f, 2048.0f), 0.0f), 4095.0f);
    return (int)x;
}

__global__ void __launch_bounds__(TPB, 8)
main_pass(const float* __restrict__ logits, const int* __restrict__ targets,
          int N, u32* __restrict__ partials, u32* __restrict__ ctrs)
{
    __shared__ u32 hist[NBIN];      // 16 KB
    const int t = threadIdx.x;
    if (blockIdx.x == 0 && t < 2) ctrs[t] = 0u;   // reset gates every launch
    for (int i = t; i < NBIN; i += TPB) hist[i] = 0u;
    __syncthreads();

    const int nQuad = N >> 2;                     // quad = 2 float4 + 1 int4
    const int gid = blockIdx.x * TPB + t;
    const int stride = NBLK * TPB;
    const float4* __restrict__ lp = (const float4*)logits;
    const int4*   __restrict__ tg = (const int4*)targets;

    int i = gid;
    for (; i + stride < nQuad; i += 2 * stride) {
        const int j = i + stride;
        float4 a0 = lp[2 * i];
        float4 b0 = lp[2 * i + 1];
        int4   t0 = tg[i];
        float4 a1 = lp[2 * j];
        float4 b1 = lp[2 * j + 1];
        int4   t1 = tg[j];
        int s0 = bin5(a0.x, a0.y), s1 = bin5(a0.z, a0.w);
        int s2 = bin5(b0.x, b0.y), s3 = bin5(b0.z, b0.w);
        int s4 = bin5(a1.x, a1.y), s5 = bin5(a1.z, a1.w);
        int s6 = bin5(b1.x, b1.y), s7 = bin5(b1.z, b1.w);
        atomicAdd(&hist[s0], 1u | ((u32)t0.x << 16));
        atomicAdd(&hist[s1], 1u | ((u32)t0.y << 16));
        atomicAdd(&hist[s2], 1u | ((u32)t0.z << 16));
        atomicAdd(&hist[s3], 1u | ((u32)t0.w << 16));
        atomicAdd(&hist[s4], 1u | ((u32)t1.x << 16));
        atomicAdd(&hist[s5], 1u | ((u32)t1.y << 16));
        atomicAdd(&hist[s6], 1u | ((u32)t1.z << 16));
        atomicAdd(&hist[s7], 1u | ((u32)t1.w << 16));
    }
    for (; i < nQuad; i += stride) {
        float4 a0 = lp[2 * i];
        float4 b0 = lp[2 * i + 1];
        int4   t0 = tg[i];
        int s0 = bin5(a0.x, a0.y), s1 = bin5(a0.z, a0.w);
        int s2 = bin5(b0.x, b0.y), s3 = bin5(b0.z, b0.w);
        atomicAdd(&hist[s0], 1u | ((u32)t0.x << 16));
        atomicAdd(&hist[s1], 1u | ((u32)t0.y << 16));
        atomicAdd(&hist[s2], 1u | ((u32)t0.z << 16));
        atomicAdd(&hist[s3], 1u | ((u32)t0.w << 16));
    }
    if (blockIdx.x == 0 && t == 0) {
        for (int x = nQuad << 2; x < N; ++x) {
            int s = bin5(logits[2 * x], logits[2 * x + 1]);
            atomicAdd(&hist[s], 1u | ((u32)targets[x] << 16));
        }
    }
    __syncthreads();

    u32* dst = partials + (size_t)blockIdx.x * NBIN;
    for (int i2 = t; i2 < NBIN; i2 += TPB) dst[i2] = hist[i2];
}

// 128 blocks x 256 threads; block owns bins [32b, 32b+32). Last block scans.
__global__ void __launch_bounds__(256)
reduce_scan(const u32* __restrict__ partials, u64* __restrict__ fineHist,
            u64* __restrict__ prefixA, u32* __restrict__ ctrs)
{
    __shared__ u32 shc[8][32];
    __shared__ u32 shp[8][32];
    __shared__ int lastFlag;
    const int t = threadIdx.x;
    const int bin = t & 31, grp = t >> 5;
    const int base = blockIdx.x * BPB;

    u32 cnt = 0u, pos = 0u;
    const u32* p = partials + (size_t)(grp * 64) * NBIN + base + bin;
    #pragma unroll 8
    for (int i = 0; i < 64; ++i) {
        u32 v = p[(size_t)i * NBIN];
        cnt += (v & 0xFFFFu);
        pos += (v >> 16);
    }
    shc[grp][bin] = cnt;
    shp[grp][bin] = pos;
    __syncthreads();
    if (t < 32) {
        u32 c = 0u, q = 0u;
        #pragma unroll
        for (int g = 0; g < 8; ++g) { c += shc[g][t]; q += shp[g][t]; }
        u64 val = (u64)c | ((u64)q << 32);
        __hip_atomic_store(&fineHist[base + t], val,
                           __ATOMIC_RELAXED, __HIP_MEMORY_SCOPE_AGENT);
    }
    __syncthreads();
    if (t == 0) {
        __threadfence();
        u32 d = __hip_atomic_fetch_add(&ctrs[0], 1u,
                                       __ATOMIC_ACQ_REL, __HIP_MEMORY_SCOPE_AGENT);
        lastFlag = (d == RBLK - 1) ? 1 : 0;
    }
    __syncthreads();
    if (!lastFlag) return;

    // ---- last block: inclusive scan of all 4096 bins -> prefixA ----
    u64 loc[16];
    u64 run = 0ULL;
    const int b0 = t * 16;
    #pragma unroll
    for (int j = 0; j < 16; ++j) {
        u64 v = __hip_atomic_load(&fineHist[b0 + j],
                                  __ATOMIC_RELAXED, __HIP_MEMORY_SCOPE_AGENT);
        run += v;
        loc[j] = run;
    }
    __shared__ u64 sh[256];
    sh[t] = run;
    __syncthreads();
    for (int off = 1; off < 256; off <<= 1) {
        u64 v = (t >= off) ? sh[t - off] : 0ULL;
        __syncthreads();
        sh[t] += v;
        __syncthreads();
    }
    u64 excl = sh[t] - run;
    #pragma unroll
    for (int j = 0; j < 16; ++j) prefixA[b0 + j] = excl + loc[j];
}

// 256 blocks x 256 threads; AP contributions; last block finalizes outputs.
__global__ void __launch_bounds__(256)
ap_finalize(const u64* __restrict__ fineHist, const u64* __restrict__ prefixA,
            double* __restrict__ apPartial, u32* __restrict__ ctrs,
            const float* __restrict__ loss, float* __restrict__ out)
{
    __shared__ double sdw[4];
    __shared__ int lastFlag;
    const int t = threadIdx.x;
    const int lane = t & 63;
    const int wave = t >> 6;
    const u64 tot = prefixA[NBIN - 1];
    const float Ntot = (float)(u32)tot;
    const float Ptot = (float)(u32)(tot >> 32);
    float acc = 0.0f;
    #pragma unroll
    for (int q = 0; q < 4; ++q) {
        int s = blockIdx.x + (wave * 4 + q) * APB;   // 16 x 256 = 4096
        u64 h = fineHist[s];
        u32 Cv = (u32)h;
        u32 Pv = (u32)(h >> 32);
        if (Pv) {
            u64 inc = prefixA[s];
            float Nb = Ntot - (float)(u32)inc;          // strictly above (desc)
            float Pb = Ptot - (float)(u32)(inc >> 32);  // positives above
            float ratio = (float)Cv / (float)Pv;
            for (u32 j = (u32)lane + 1u; j <= Pv; j += 64u) {
                float jf = (float)j;
                float rank = Nb + (jf - 0.5f) * ratio + 0.5f;
                acc += (Pb + jf) * __builtin_amdgcn_rcpf(rank);
            }
        }
    }
    double dacc = (double)acc;
    #pragma unroll
    for (int off = 32; off > 0; off >>= 1)
        dacc += __shfl_down(dacc, off);
    if (lane == 0) sdw[wave] = dacc;
    __syncthreads();
    if (t == 0) {
        double v = sdw[0] + sdw[1] + sdw[2] + sdw[3];
        __hip_atomic_store((u64*)&apPartial[blockIdx.x],
                           (u64)__double_as_longlong(v),
                           __ATOMIC_RELAXED, __HIP_MEMORY_SCOPE_AGENT);
        __threadfence();
        u32 d = __hip_atomic_fetch_add(&ctrs[1], 1u,
                                       __ATOMIC_ACQ_REL, __HIP_MEMORY_SCOPE_AGENT);
        lastFlag = (d == APB - 1) ? 1 : 0;
    }
    __syncthreads();
    if (!lastFlag) return;

    // ---- last block: fold AP partials + write all outputs ----
    __shared__ double sd[256];
    u64 raw = __hip_atomic_load((u64*)&apPartial[t],
                                __ATOMIC_RELAXED, __HIP_MEMORY_SCOPE_AGENT);
    sd[t] = __longlong_as_double((long long)raw);
    __syncthreads();
    for (int off = 128; off > 0; off >>= 1) {
        if (t < off) sd[t] += sd[t + off];
        __syncthreads();
    }

    const u32 Ncnt = (u32)tot;
    const u32 Pcnt = (u32)(tot >> 32);

    if (t <= 100) {
        // boundary position in bin space: x = logit(th)*256 + 2048
        double th = (double)((float)t * 0.01f);
        double x  = log(th / (1.0 - th)) * 256.0 + 2048.0;   // -inf/+inf ok
        x = fmin(fmax(x, 0.0), 4096.0);
        int bk = (int)x; if (bk > NBIN - 1) bk = NBIN - 1;
        double frac = x - (double)bk;
        u64 ex = (bk > 0) ? prefixA[bk - 1] : 0ULL;
        u64 h  = fineHist[bk];
        double cb = (double)(u32)ex + frac * (double)(u32)h;          // p1<=th
        double pb = (double)(u32)(ex >> 32) + frac * (double)(u32)(h >> 32);
        float idx_f = (float)cb;
        float fn_t  = (float)pb;
        float tp_t  = (float)Pcnt - fn_t;
        float tn_t  = idx_f - fn_t;
        float fp_t  = (float)Ncnt - idx_f - tp_t;
        out[5 + t]   = safe_div_f(tp_t, tp_t + fp_t);  // prec_t
        out[106 + t] = safe_div_f(tp_t, tp_t + fn_t);  // rec_t
        out[207 + t] = (float)t * 0.01f;               // ths
        out[308 + t] = safe_div_f(tn_t, tn_t + fp_t);  // spec_t
    }

    if (t == 0) {
        u64 pv = prefixA[2047];             // d < 0  (bin 2048 starts at d=0)
        u32 lowC = (u32)pv, lowP = (u32)(pv >> 32);
        float tp0 = (float)(Pcnt - lowP);
        float fn0 = (float)lowP;
        float tn0 = (float)(lowC - lowP);
        float fp0 = (float)(Ncnt - lowC) - tp0;
        float nF  = (float)Ncnt;
        out[0] = tn0; out[1] = fp0; out[2] = fn0; out[3] = tp0;
        double denom = (Pcnt > 0u) ? (double)Pcnt : 1.0;
        out[4] = (float)(sd[0] / denom);
        out[409] = safe_div_f(tp0, tp0 + fn0);
        out[410] = safe_div_f(tp0, tp0 + fp0);
        out[411] = safe_div_f(tn0, tn0 + fp0);
        out[412] = (tp0 + tn0) / nF;
        out[413] = (loss[0] + loss[1] + loss[2] + loss[3]) * 0.25f;
    }
}

extern "C" void kernel_launch(void* const* d_in, const int* in_sizes, int n_in,
                              void* d_out, int out_size, void* d_ws, size_t ws_size,
                              hipStream_t stream)
{
    const float* logits  = (const float*)d_in[0];
    const int*   targets = (const int*)d_in[1];
    const float* loss    = (const float*)d_in[2];
    const int N = in_sizes[1];

    char* ws = (char*)d_ws;
    size_t off = 0;
    u32* partials = (u32*)(ws + off);   off += (size_t)NBLK * NBIN * 4;  // 8 MB
    u64* fineHist = (u64*)(ws + off);   off += (size_t)NBIN * 8;         // 32 KB
    u64* prefixA  = (u64*)(ws + off);   off += (size_t)NBIN * 8;         // 32 KB
    double* apPartial = (double*)(ws + off); off += (size_t)APB * 8;     // 2 KB
    u32* ctrs     = (u32*)(ws + off);

    main_pass<<<NBLK, TPB, 0, stream>>>(logits, targets, N, partials, ctrs);
    reduce_scan<<<RBLK, 256, 0, stream>>>(partials, fineHist, prefixA, ctrs);
    ap_finalize<<<APB, 256, 0, stream>>>(fineHist, prefixA, apPartial, ctrs,
                                         loss, (float*)d_out);
}